// Round 1
// baseline (145.229 us; speedup 1.0000x reference)
//
#include <hip/hip_runtime.h>
#include <stdint.h>

#define BB 4
#define CC 64
#define HH 64
#define WW 192
#define DD 24
#define HWQ (HH * WW)            // 12288 pixels per image plane
#define PIX (BB * HWQ)           // 49152 pixels per volume side

typedef __attribute__((ext_vector_type(8))) short short8;
typedef __attribute__((ext_vector_type(4))) float floatx4;

// ---------- bf16 helpers ----------
__device__ __forceinline__ float bf1(uint16_t u) {
    union { uint32_t i; float f; } c; c.i = ((uint32_t)u) << 16; return c.f;
}
__device__ __forceinline__ uint16_t f2bf(float f) {  // RNE, finite inputs only
    union { float f; uint32_t i; } c; c.f = f;
    uint32_t u = c.i;
    return (uint16_t)((u + 0x7fffu + ((u >> 16) & 1u)) >> 16);
}

// ws layout (shorts from base):
//   A:   [2][PIX][CC] bf16                       (6,291,456 shorts)
//   Ybf: [2][BB][CC][HH][WW] bf16 mirror of x,y  (6,291,456 shorts)
//   f32 region: s[2*PIX] @4240 (weights now computed per-block in LDS).
#define A_SHORTS ((size_t)2 * PIX * CC)
#define S_F32OFF 4240

// =====================================================================
// convA (prep absorbed): per-block compute G[64][64], beta, alpha, gamma
// in LDS (identical fma order to old prep), then the proven VALU conv:
// A[v][pix][j] = bf16(X.G[:,j]+beta[j]), s[v][pix] = alpha.X + gamma,
// plus bf16 mirror Ybf[v]. Block (64,8): 8 waves (12 waves/CU avg vs 6
// before), each thread 4 px x 8 j.
// grid (PIX/256, 2), block (64,8).
// =====================================================================
__global__ __launch_bounds__(512) void convA_kernel(
    const float* __restrict__ x, const float* __restrict__ y,
    const float* __restrict__ qw, const float* __restrict__ qb,
    const float* __restrict__ kw, const float* __restrict__ kb,
    float* __restrict__ fws, uint16_t* __restrict__ A,
    uint16_t* __restrict__ Ybf) {
    const int v = blockIdx.y;
    const float* src = v ? y : x;
    float* s = fws + S_F32OFF;

    __shared__ float wt[64][64];   // wt[i][j] = G[i][j]
    __shared__ float bs[64], al[64];
    __shared__ float gm;

    const int tx  = threadIdx.x;           // 0..63 (lane)
    const int ty  = threadIdx.y;           // 0..7 (wave)
    const int tid = ty * 64 + tx;

    // ---- weights in-block: G[i][j] = sum_c qw[c,i]*kw[c,j] (same order) ----
    {
        float ga[8];
#pragma unroll
        for (int k = 0; k < 8; k++) ga[k] = 0.f;
        for (int c = 0; c < 64; c++) {
            const float kwv = kw[c * CC + tx];        // coalesced, L1/L2-hot
#pragma unroll
            for (int k = 0; k < 8; k++)
                ga[k] = fmaf(qw[c * CC + (k * 8 + ty)], kwv, ga[k]);  // wave-uniform
        }
#pragma unroll
        for (int k = 0; k < 8; k++) wt[k * 8 + ty][tx] = ga[k];
    }
    if (tid < 64) {
        float bt = 0.f;
        for (int c = 0; c < 64; c++) bt = fmaf(qb[c], kw[c * CC + tid], bt);
        bs[tid] = bt;
    } else if (tid < 128) {
        const int i = tid - 64;
        float a = 0.f;
        for (int c = 0; c < 64; c++) a = fmaf(qw[c * CC + i], kb[c], a);
        al[i] = a;
    } else if (tid == 128) {
        float g = 0.f;
        for (int c = 0; c < 64; c++) g = fmaf(qb[c], kb[c], g);
        gm = g;
    }
    __syncthreads();

    const int pix0 = blockIdx.x * 256 + tx * 4;
    const int b    = pix0 / HWQ;
    const int hw0  = pix0 - b * HWQ;
    const int j0   = ty * 8;

    float acc[4][8];
#pragma unroll
    for (int p = 0; p < 4; p++)
#pragma unroll
        for (int k = 0; k < 8; k++) acc[p][k] = bs[j0 + k];
    float sac[4] = {gm, gm, gm, gm};

    const float*    sp   = src + (size_t)b * CC * HWQ + hw0;
    uint16_t*       Ymir = Ybf + (size_t)v * PIX * CC + (size_t)b * CC * HWQ + hw0;
#pragma unroll 4
    for (int i = 0; i < 64; i++) {
        float4 raw = *reinterpret_cast<const float4*>(sp + (size_t)i * HWQ);
        if ((i & 7) == ty) {   // wave-uniform: this wave mirrors channel i
            uint2 pv;
            pv.x = (uint32_t)f2bf(raw.x) | ((uint32_t)f2bf(raw.y) << 16);
            pv.y = (uint32_t)f2bf(raw.z) | ((uint32_t)f2bf(raw.w) << 16);
            *reinterpret_cast<uint2*>(Ymir + (size_t)i * HWQ) = pv;
        }
        const float* wr = &wt[i][j0];   // wave-uniform -> LDS broadcast
        if (ty == 0) {                  // wave-uniform: only wave 0 owns s
            const float av = al[i];
            sac[0] = fmaf(raw.x, av, sac[0]);
            sac[1] = fmaf(raw.y, av, sac[1]);
            sac[2] = fmaf(raw.z, av, sac[2]);
            sac[3] = fmaf(raw.w, av, sac[3]);
        }
#pragma unroll
        for (int k = 0; k < 8; k++) {
            float wv = wr[k];
            acc[0][k] = fmaf(raw.x, wv, acc[0][k]);
            acc[1][k] = fmaf(raw.y, wv, acc[1][k]);
            acc[2][k] = fmaf(raw.z, wv, acc[2][k]);
            acc[3][k] = fmaf(raw.w, wv, acc[3][k]);
        }
    }

    uint16_t* dstv = A + (size_t)v * PIX * CC;
#pragma unroll
    for (int p = 0; p < 4; p++) {
        uint32_t pk[4];
#pragma unroll
        for (int k = 0; k < 4; k++)
            pk[k] = (uint32_t)f2bf(acc[p][2 * k]) | ((uint32_t)f2bf(acc[p][2 * k + 1]) << 16);
        uint16_t* dp = dstv + (size_t)(pix0 + p) * CC + j0;
        uint4 w4; w4.x = pk[0]; w4.y = pk[1]; w4.z = pk[2]; w4.w = pk[3];
        *reinterpret_cast<uint4*>(dp) = w4;   // 16B per pixel (8 bf16)
    }
    if (ty == 0) {
        float4 sv; sv.x = sac[0]; sv.y = sac[1]; sv.z = sac[2]; sv.w = sac[3];
        *reinterpret_cast<float4*>(s + (size_t)v * PIX + pix0) = sv;
    }
}

// =====================================================================
// Cost (R11 structure + latency hoists): ONE block per (h, b, v), 1024
// threads. NEW: A-fragments for BOTH halves (16 VGPR) and the epilogue's
// disp/s values (12 VGPR) are loaded into registers BEFORE the Yc
// staging barrier, so their HBM/L2 latency overlaps staging instead of
// stalling the serial MFMA/epilogue phases.
// grid (HH, BB, 2), block 1024.
// =====================================================================
__global__ __launch_bounds__(1024) void cost_kernel(
    const float* __restrict__ disp1, const float* __restrict__ disp2,
    const uint16_t* __restrict__ A, const uint16_t* __restrict__ Ybf,
    const float* __restrict__ fws, float* __restrict__ out) {
    const int h = blockIdx.x;
    const int b = blockIdx.y;
    const int v = blockIdx.z;

    const int       tsel = v ? 0 : 1;          // v=0 gathers y (=Ybf[1]), v=1 gathers x (=Ybf[0])
    const float*    disp = v ? disp2 : disp1;
    const uint16_t* Ab   = A + ((size_t)v * PIX + (size_t)b * HWQ + h * WW) * CC;
    const float*    sb   = fws + S_F32OFF + (size_t)v * PIX + (size_t)b * HWQ + h * WW;

    // ---- row geometry (uniform) ----
    const float ys  = (float)h * (float)(64.0 / 63.0) - 0.5f;
    const float y0f = floorf(ys);
    const float ty  = ys - y0f;
    const int   y0  = (int)y0f;
    const int   y1  = y0 + 1;
    const float vy0 = (y0 >= 0 && y0 < HH) ? 1.f : 0.f;
    const float vy1 = (y1 >= 0 && y1 < HH) ? 1.f : 0.f;
    const int   y0c = min(max(y0, 0), HH - 1);
    const int   y1c = min(max(y1, 0), HH - 1);
    const float ey0 = (1.f - ty) * vy0;
    const float ey1 = ty * vy1;
    const float eysum = ey0 + ey1;

    __shared__ uint16_t Yc[192 * 68];   // 26,112 B: combined row, [x][c]
    __shared__ uint16_t Pt[96 * 196];   // 37,632 B: [w_half_local][x]

    const int tid  = threadIdx.x;
    const int wave = tid >> 6;
    const int lane = tid & 63;
    const int lq   = lane >> 4;
    const int ln   = lane & 15;

    // ---- HOIST 1: A-fragments for both halves, before any barrier ----
    short8 a0f[2], a1f[2];
    if (wave < 12) {
        const int mcl = wave >> 1;                    // local m-chunk 0..5
#pragma unroll
        for (int hf = 0; hf < 2; hf++) {
            const uint16_t* ar = Ab + (size_t)(hf * 96 + mcl * 16 + ln) * CC + lq * 8;
            a0f[hf] = *reinterpret_cast<const short8*>(ar);
            a1f[hf] = *reinterpret_cast<const short8*>(ar + 32);
        }
    }

    // ---- HOIST 2: epilogue disp + s values into registers ----
    float dpre[2][3], spre[2][3];
#pragma unroll
    for (int hf = 0; hf < 2; hf++)
#pragma unroll
        for (int q = 0; q < 3; q++) { dpre[hf][q] = 0.f; spre[hf][q] = 0.f; }
#pragma unroll
    for (int hf = 0; hf < 2; hf++) {
#pragma unroll
        for (int q = 0; q < 3; q++) {
            const int o = tid + q * 1024;
            if (o < 96 * DD) {
                const int wl = o % 96;
                const int d  = o / 96;
                const int w  = hf * 96 + wl;
                dpre[hf][q] = disp[((size_t)(b * DD + d) * HH + h) * WW + w];
                spre[hf][q] = sb[w];
            }
        }
    }

    // ---- stage Yc once from bf16 mirror: wave = c-group, x = k*64+lane ----
    const uint16_t* Yb0 = Ybf + (size_t)tsel * PIX * CC + (size_t)b * CC * HWQ + y0c * WW;
    const uint16_t* Yb1 = Ybf + (size_t)tsel * PIX * CC + (size_t)b * CC * HWQ + y1c * WW;
#pragma unroll
    for (int k = 0; k < 3; k++) {
        const int cg = wave;
        const int xx = k * 64 + lane;
        uint32_t pk[2];
#pragma unroll
        for (int half = 0; half < 2; half++) {
            uint32_t pv = 0;
#pragma unroll
            for (int j = 0; j < 2; j++) {
                const int c = cg * 4 + half * 2 + j;
                const float v0 = bf1(Yb0[(size_t)c * HWQ + xx]);
                const float v1 = bf1(Yb1[(size_t)c * HWQ + xx]);
                const float cb = fmaf(ey1, v1, ey0 * v0);
                pv |= ((uint32_t)f2bf(cb)) << (16 * j);
            }
            pk[half] = pv;
        }
        *reinterpret_cast<uint2*>(&Yc[xx * 68 + cg * 4]) = *reinterpret_cast<uint2*>(pk);
    }
    __syncthreads();

    const float cx = (float)(192.0 / 191.0);
    const float inv_c = 1.f / 64.f;

#pragma unroll
    for (int half = 0; half < 2; half++) {
        // ---- MFMA: 6 m-chunks x 12 n-tiles; waves 0..11, A-frag reused x6 ----
        if (wave < 12) {
            const int mcl = wave >> 1;
            const short8 a0 = a0f[half];
            const short8 a1 = a1f[half];
#pragma unroll
            for (int i = 0; i < 6; i++) {
                const int nt = (wave & 1) * 6 + i;
                const int Rb = nt * 16;
                const uint16_t* yrow = &Yc[(Rb + ln) * 68 + lq * 8];
                short8 b0, b1;
                *reinterpret_cast<uint2*>(&b0)       = *reinterpret_cast<const uint2*>(yrow);
                *(reinterpret_cast<uint2*>(&b0) + 1) = *reinterpret_cast<const uint2*>(yrow + 4);
                *reinterpret_cast<uint2*>(&b1)       = *reinterpret_cast<const uint2*>(yrow + 32);
                *(reinterpret_cast<uint2*>(&b1) + 1) = *reinterpret_cast<const uint2*>(yrow + 36);
                floatx4 acc = {0.f, 0.f, 0.f, 0.f};
                acc = __builtin_amdgcn_mfma_f32_16x16x32_bf16(a0, b0, acc, 0, 0, 0);
                acc = __builtin_amdgcn_mfma_f32_16x16x32_bf16(a1, b1, acc, 0, 0, 0);
                // C: col(N)=ln -> x' ; row(M)=lq*4+reg -> w_local
                const int pcol = Rb + ln;
                const int wl   = mcl * 16 + lq * 4;
                Pt[(wl + 0) * 196 + pcol] = f2bf(acc[0]);
                Pt[(wl + 1) * 196 + pcol] = f2bf(acc[1]);
                Pt[(wl + 2) * 196 + pcol] = f2bf(acc[2]);
                Pt[(wl + 3) * 196 + pcol] = f2bf(acc[3]);
            }
        }
        __syncthreads();

        // ---- epilogue: 96 w x 24 d outputs, all inputs already in regs ----
#pragma unroll
        for (int q = 0; q < 3; q++) {
            const int o = tid + q * 1024;
            if (o < 96 * DD) {
                const int wl = o % 96;           // local w within half
                const int d  = o / 96;
                const int w  = half * 96 + wl;
                const float dsv = dpre[half][q];
                const float xs  = dsv * cx - 0.5f;
                const float x0f = floorf(xs);
                const float tx  = xs - x0f;
                const int   x0  = (int)x0f;
                const int   x1  = x0 + 1;
                const float vx0 = (x0 >= 0 && x0 < WW) ? 1.f : 0.f;
                const float vx1 = (x1 >= 0 && x1 < WW) ? 1.f : 0.f;
                const int   x0c = min(max(x0, 0), WW - 1);
                const int   x1c = min(max(x1, 0), WW - 1);
                const float wx0 = (1.f - tx) * vx0;
                const float wx1 = tx * vx1;
                const float pc0 = bf1(Pt[wl * 196 + x0c]);
                const float pc1 = bf1(Pt[wl * 196 + x1c]);
                const float res = wx0 * pc0 + wx1 * pc1 + spre[half][q] * (eysum * (wx0 + wx1));
                out[(((size_t)(v * BB + b) * DD + d) * HH + h) * WW + w] = res * inv_c;
            }
        }
        if (half == 0) __syncthreads();   // protect Pt before half-1 MFMA writes
    }
}

// =====================================================================
extern "C" void kernel_launch(void* const* d_in, const int* in_sizes, int n_in,
                              void* d_out, int out_size, void* d_ws, size_t ws_size,
                              hipStream_t stream) {
    const float* x  = (const float*)d_in[0];
    const float* y  = (const float*)d_in[1];
    const float* d1 = (const float*)d_in[2];
    const float* d2 = (const float*)d_in[3];
    // d_in[4] = ndisp (int32) — compile-time DD=24
    const float* qw = (const float*)d_in[5];
    const float* qb = (const float*)d_in[6];
    const float* kw = (const float*)d_in[7];
    const float* kb = (const float*)d_in[8];

    uint16_t* A   = (uint16_t*)d_ws;
    uint16_t* Ybf = (uint16_t*)d_ws + A_SHORTS;
    float*    fws = (float*)((uint16_t*)d_ws + 2 * A_SHORTS);
    float*    out = (float*)d_out;

    convA_kernel<<<dim3(PIX / 256, 2), dim3(64, 8), 0, stream>>>(
        x, y, qw, qb, kw, kb, fws, A, Ybf);
    cost_kernel<<<dim3(HH, BB, 2), dim3(1024), 0, stream>>>(d1, d2, A, Ybf, fws, out);
}

// Round 2
// 128.072 us; speedup vs baseline: 1.1340x; 1.1340x over previous
//
#include <hip/hip_runtime.h>
#include <stdint.h>

#define BB 4
#define CC 64
#define HH 64
#define WW 192
#define DD 24
#define HWQ (HH * WW)            // 12288 pixels per image plane
#define PIX (BB * HWQ)           // 49152 pixels per volume side

typedef __attribute__((ext_vector_type(8))) short short8;
typedef __attribute__((ext_vector_type(4))) float floatx4;

// ---------- bf16 helpers ----------
__device__ __forceinline__ float bf1(uint16_t u) {
    union { uint32_t i; float f; } c; c.i = ((uint32_t)u) << 16; return c.f;
}
__device__ __forceinline__ uint16_t f2bf(float f) {  // RNE, finite inputs only
    union { float f; uint32_t i; } c; c.f = f;
    uint32_t u = c.i;
    return (uint16_t)((u + 0x7fffu + ((u >> 16) & 1u)) >> 16);
}

// ws layout (shorts from base):
//   A:   [2][PIX][CC] bf16                       (6,291,456 shorts)
//   Ybf: [2][BB][CC][HH][WW] bf16 mirror of x,y  (6,291,456 shorts)
//   f32 region: G[4096], beta[64], alpha[64], gamma[1], pad, s[2*PIX] @4240.
#define A_SHORTS ((size_t)2 * PIX * CC)
#define S_F32OFF 4240

// =====================================================================
// Prep (parallel): blocks 0..63: G[i][j] = sum_c qw[c,i]*kw[c,j]
// block 64: beta[j] = sum_c qb[c]*kw[c,j] (+gamma on t0); block 65: alpha.
// unroll 8: same fma order (bit-exact), loads hoisted for ILP.
// grid 66, block 64.
// =====================================================================
__global__ __launch_bounds__(64) void prep_kernel(
    const float* __restrict__ qw, const float* __restrict__ qb,
    const float* __restrict__ kw, const float* __restrict__ kb,
    float* __restrict__ fws) {
    const int bid = blockIdx.x;
    const int j   = threadIdx.x;
    if (bid < 64) {
        float acc = 0.f;
#pragma unroll 8
        for (int c = 0; c < CC; c++)
            acc = fmaf(qw[c * CC + bid], kw[c * CC + j], acc);  // qw read wave-uniform
        fws[bid * 64 + j] = acc;
    } else if (bid == 64) {
        float bt = 0.f;
#pragma unroll 8
        for (int c = 0; c < CC; c++) bt = fmaf(qb[c], kw[c * CC + j], bt);
        fws[4096 + j] = bt;
        if (j == 0) {
            float g = 0.f;
#pragma unroll 8
            for (int c = 0; c < CC; c++) g = fmaf(qb[c], kb[c], g);
            fws[4224] = g;
        }
    } else {
        float al = 0.f;
#pragma unroll 8
        for (int c = 0; c < CC; c++) al = fmaf(qw[c * CC + j], kb[c], al);
        fws[4160 + j] = al;
    }
}

// =====================================================================
// convA (R0 structure, 2 px/thread): A[v][pix][j] = bf16(X.G[:,j]+beta[j]),
// s[v][pix] = alpha.X + gamma, plus bf16 mirror Ybf[v]. Identical fma
// order to the 127.6 µs baseline (bit-exact); only the pixel partition
// changed: 128 px/block -> 3072 waves (3/SIMD) for latency hiding.
// grid (PIX/128, 2), block (64,4).
// =====================================================================
__global__ __launch_bounds__(256) void convA_kernel(
    const float* __restrict__ x, const float* __restrict__ y,
    float* __restrict__ fws, uint16_t* __restrict__ A,
    uint16_t* __restrict__ Ybf) {
    const int v = blockIdx.y;
    const float* src = v ? y : x;
    float* s = fws + S_F32OFF;

    __shared__ float wt[64][64];   // wt[i][j] = G[i][j]
    __shared__ float bs[64], al[64];
    __shared__ float gm;
    const int tid = threadIdx.y * 64 + threadIdx.x;
    for (int idx = tid; idx < 4096; idx += 256) wt[idx >> 6][idx & 63] = fws[idx];
    if (tid < 64) { bs[tid] = fws[4096 + tid]; al[tid] = fws[4160 + tid]; }
    if (tid == 64) gm = fws[4224];
    __syncthreads();

    const int pix0 = blockIdx.x * 128 + threadIdx.x * 2;
    const int b    = pix0 / HWQ;
    const int hw0  = pix0 - b * HWQ;
    const int j0   = threadIdx.y * 16;

    float acc[2][16];
#pragma unroll
    for (int p = 0; p < 2; p++)
#pragma unroll
        for (int k = 0; k < 16; k++) acc[p][k] = bs[j0 + k];
    float sac[2] = {gm, gm};

    const float*    sp   = src + (size_t)b * CC * HWQ + hw0;
    uint16_t*       Ymir = Ybf + (size_t)v * PIX * CC + (size_t)b * CC * HWQ + hw0;
#pragma unroll 4
    for (int i = 0; i < 64; i++) {
        float2 raw = *reinterpret_cast<const float2*>(sp + (size_t)i * HWQ);
        if ((i & 3) == threadIdx.y) {   // wave-uniform: this wave mirrors channel i
            uint32_t pv = (uint32_t)f2bf(raw.x) | ((uint32_t)f2bf(raw.y) << 16);
            *reinterpret_cast<uint32_t*>(Ymir + (size_t)i * HWQ) = pv;
        }
        const float* wr = &wt[i][j0];   // wave-uniform -> LDS broadcast
        const float av = al[i];
        sac[0] = fmaf(raw.x, av, sac[0]);
        sac[1] = fmaf(raw.y, av, sac[1]);
#pragma unroll
        for (int k = 0; k < 16; k++) {
            float wv = wr[k];
            acc[0][k] = fmaf(raw.x, wv, acc[0][k]);
            acc[1][k] = fmaf(raw.y, wv, acc[1][k]);
        }
    }

    uint16_t* dstv = A + (size_t)v * PIX * CC;
#pragma unroll
    for (int p = 0; p < 2; p++) {
        uint32_t pk[8];
#pragma unroll
        for (int k = 0; k < 8; k++)
            pk[k] = (uint32_t)f2bf(acc[p][2 * k]) | ((uint32_t)f2bf(acc[p][2 * k + 1]) << 16);
        uint16_t* dp = dstv + (size_t)(pix0 + p) * CC + j0;
        uint4 lo; lo.x = pk[0]; lo.y = pk[1]; lo.z = pk[2]; lo.w = pk[3];
        uint4 hi; hi.x = pk[4]; hi.y = pk[5]; hi.z = pk[6]; hi.w = pk[7];
        *reinterpret_cast<uint4*>(dp)     = lo;
        *reinterpret_cast<uint4*>(dp + 8) = hi;
    }
    if (threadIdx.y == 0) {
        float2 sv; sv.x = sac[0]; sv.y = sac[1];
        *reinterpret_cast<float2*>(s + (size_t)v * PIX + pix0) = sv;
    }
}

// =====================================================================
// Cost (R11 structure + latency hoists): ONE block per (h, b, v), 1024
// threads. A-fragments for BOTH halves (16 VGPR) and the epilogue's
// disp/s values (12 VGPR) are loaded into registers BEFORE the Yc
// staging barrier, so their HBM/L2 latency overlaps staging instead of
// stalling the serial MFMA/epilogue phases.
// grid (HH, BB, 2), block 1024.
// =====================================================================
__global__ __launch_bounds__(1024) void cost_kernel(
    const float* __restrict__ disp1, const float* __restrict__ disp2,
    const uint16_t* __restrict__ A, const uint16_t* __restrict__ Ybf,
    const float* __restrict__ fws, float* __restrict__ out) {
    const int h = blockIdx.x;
    const int b = blockIdx.y;
    const int v = blockIdx.z;

    const int       tsel = v ? 0 : 1;          // v=0 gathers y (=Ybf[1]), v=1 gathers x (=Ybf[0])
    const float*    disp = v ? disp2 : disp1;
    const uint16_t* Ab   = A + ((size_t)v * PIX + (size_t)b * HWQ + h * WW) * CC;
    const float*    sb   = fws + S_F32OFF + (size_t)v * PIX + (size_t)b * HWQ + h * WW;

    // ---- row geometry (uniform) ----
    const float ys  = (float)h * (float)(64.0 / 63.0) - 0.5f;
    const float y0f = floorf(ys);
    const float ty  = ys - y0f;
    const int   y0  = (int)y0f;
    const int   y1  = y0 + 1;
    const float vy0 = (y0 >= 0 && y0 < HH) ? 1.f : 0.f;
    const float vy1 = (y1 >= 0 && y1 < HH) ? 1.f : 0.f;
    const int   y0c = min(max(y0, 0), HH - 1);
    const int   y1c = min(max(y1, 0), HH - 1);
    const float ey0 = (1.f - ty) * vy0;
    const float ey1 = ty * vy1;
    const float eysum = ey0 + ey1;

    __shared__ uint16_t Yc[192 * 68];   // 26,112 B: combined row, [x][c]
    __shared__ uint16_t Pt[96 * 196];   // 37,632 B: [w_half_local][x]

    const int tid  = threadIdx.x;
    const int wave = tid >> 6;
    const int lane = tid & 63;
    const int lq   = lane >> 4;
    const int ln   = lane & 15;

    // ---- HOIST 1: A-fragments for both halves, before any barrier ----
    short8 a0f[2], a1f[2];
    if (wave < 12) {
        const int mcl = wave >> 1;                    // local m-chunk 0..5
#pragma unroll
        for (int hf = 0; hf < 2; hf++) {
            const uint16_t* ar = Ab + (size_t)(hf * 96 + mcl * 16 + ln) * CC + lq * 8;
            a0f[hf] = *reinterpret_cast<const short8*>(ar);
            a1f[hf] = *reinterpret_cast<const short8*>(ar + 32);
        }
    }

    // ---- HOIST 2: epilogue disp + s values into registers ----
    float dpre[2][3], spre[2][3];
#pragma unroll
    for (int hf = 0; hf < 2; hf++)
#pragma unroll
        for (int q = 0; q < 3; q++) { dpre[hf][q] = 0.f; spre[hf][q] = 0.f; }
#pragma unroll
    for (int hf = 0; hf < 2; hf++) {
#pragma unroll
        for (int q = 0; q < 3; q++) {
            const int o = tid + q * 1024;
            if (o < 96 * DD) {
                const int wl = o % 96;
                const int d  = o / 96;
                const int w  = hf * 96 + wl;
                dpre[hf][q] = disp[((size_t)(b * DD + d) * HH + h) * WW + w];
                spre[hf][q] = sb[w];
            }
        }
    }

    // ---- stage Yc once from bf16 mirror: wave = c-group, x = k*64+lane ----
    const uint16_t* Yb0 = Ybf + (size_t)tsel * PIX * CC + (size_t)b * CC * HWQ + y0c * WW;
    const uint16_t* Yb1 = Ybf + (size_t)tsel * PIX * CC + (size_t)b * CC * HWQ + y1c * WW;
#pragma unroll
    for (int k = 0; k < 3; k++) {
        const int cg = wave;
        const int xx = k * 64 + lane;
        uint32_t pk[2];
#pragma unroll
        for (int half = 0; half < 2; half++) {
            uint32_t pv = 0;
#pragma unroll
            for (int j = 0; j < 2; j++) {
                const int c = cg * 4 + half * 2 + j;
                const float v0 = bf1(Yb0[(size_t)c * HWQ + xx]);
                const float v1 = bf1(Yb1[(size_t)c * HWQ + xx]);
                const float cb = fmaf(ey1, v1, ey0 * v0);
                pv |= ((uint32_t)f2bf(cb)) << (16 * j);
            }
            pk[half] = pv;
        }
        *reinterpret_cast<uint2*>(&Yc[xx * 68 + cg * 4]) = *reinterpret_cast<uint2*>(pk);
    }
    __syncthreads();

    const float cx = (float)(192.0 / 191.0);
    const float inv_c = 1.f / 64.f;

#pragma unroll
    for (int half = 0; half < 2; half++) {
        // ---- MFMA: 6 m-chunks x 12 n-tiles; waves 0..11, A-frag reused x6 ----
        if (wave < 12) {
            const int mcl = wave >> 1;
            const short8 a0 = a0f[half];
            const short8 a1 = a1f[half];
#pragma unroll
            for (int i = 0; i < 6; i++) {
                const int nt = (wave & 1) * 6 + i;
                const int Rb = nt * 16;
                const uint16_t* yrow = &Yc[(Rb + ln) * 68 + lq * 8];
                short8 b0, b1;
                *reinterpret_cast<uint2*>(&b0)       = *reinterpret_cast<const uint2*>(yrow);
                *(reinterpret_cast<uint2*>(&b0) + 1) = *reinterpret_cast<const uint2*>(yrow + 4);
                *reinterpret_cast<uint2*>(&b1)       = *reinterpret_cast<const uint2*>(yrow + 32);
                *(reinterpret_cast<uint2*>(&b1) + 1) = *reinterpret_cast<const uint2*>(yrow + 36);
                floatx4 acc = {0.f, 0.f, 0.f, 0.f};
                acc = __builtin_amdgcn_mfma_f32_16x16x32_bf16(a0, b0, acc, 0, 0, 0);
                acc = __builtin_amdgcn_mfma_f32_16x16x32_bf16(a1, b1, acc, 0, 0, 0);
                // C: col(N)=ln -> x' ; row(M)=lq*4+reg -> w_local
                const int pcol = Rb + ln;
                const int wl   = mcl * 16 + lq * 4;
                Pt[(wl + 0) * 196 + pcol] = f2bf(acc[0]);
                Pt[(wl + 1) * 196 + pcol] = f2bf(acc[1]);
                Pt[(wl + 2) * 196 + pcol] = f2bf(acc[2]);
                Pt[(wl + 3) * 196 + pcol] = f2bf(acc[3]);
            }
        }
        __syncthreads();

        // ---- epilogue: 96 w x 24 d outputs, all inputs already in regs ----
#pragma unroll
        for (int q = 0; q < 3; q++) {
            const int o = tid + q * 1024;
            if (o < 96 * DD) {
                const int wl = o % 96;           // local w within half
                const int d  = o / 96;
                const int w  = half * 96 + wl;
                const float dsv = dpre[half][q];
                const float xs  = dsv * cx - 0.5f;
                const float x0f = floorf(xs);
                const float tx  = xs - x0f;
                const int   x0  = (int)x0f;
                const int   x1  = x0 + 1;
                const float vx0 = (x0 >= 0 && x0 < WW) ? 1.f : 0.f;
                const float vx1 = (x1 >= 0 && x1 < WW) ? 1.f : 0.f;
                const int   x0c = min(max(x0, 0), WW - 1);
                const int   x1c = min(max(x1, 0), WW - 1);
                const float wx0 = (1.f - tx) * vx0;
                const float wx1 = tx * vx1;
                const float pc0 = bf1(Pt[wl * 196 + x0c]);
                const float pc1 = bf1(Pt[wl * 196 + x1c]);
                const float res = wx0 * pc0 + wx1 * pc1 + spre[half][q] * (eysum * (wx0 + wx1));
                out[(((size_t)(v * BB + b) * DD + d) * HH + h) * WW + w] = res * inv_c;
            }
        }
        if (half == 0) __syncthreads();   // protect Pt before half-1 MFMA writes
    }
}

// =====================================================================
extern "C" void kernel_launch(void* const* d_in, const int* in_sizes, int n_in,
                              void* d_out, int out_size, void* d_ws, size_t ws_size,
                              hipStream_t stream) {
    const float* x  = (const float*)d_in[0];
    const float* y  = (const float*)d_in[1];
    const float* d1 = (const float*)d_in[2];
    const float* d2 = (const float*)d_in[3];
    // d_in[4] = ndisp (int32) — compile-time DD=24
    const float* qw = (const float*)d_in[5];
    const float* qb = (const float*)d_in[6];
    const float* kw = (const float*)d_in[7];
    const float* kb = (const float*)d_in[8];

    uint16_t* A   = (uint16_t*)d_ws;
    uint16_t* Ybf = (uint16_t*)d_ws + A_SHORTS;
    float*    fws = (float*)((uint16_t*)d_ws + 2 * A_SHORTS);
    float*    out = (float*)d_out;

    prep_kernel<<<dim3(66), dim3(64), 0, stream>>>(qw, qb, kw, kb, fws);
    convA_kernel<<<dim3(PIX / 128, 2), dim3(64, 4), 0, stream>>>(x, y, fws, A, Ybf);
    cost_kernel<<<dim3(HH, BB, 2), dim3(1024), 0, stream>>>(d1, d2, A, Ybf, fws, out);
}